// Round 14
// baseline (182.592 us; speedup 1.0000x reference)
//
#include <hip/hip_runtime.h>
#include <hip/hip_bf16.h>
#include <math.h>
#include <float.h>

// Problem constants (fixed by setup_inputs)
#define BATCH 108
#define NNODE 392
#define IDIM  256
#define HEADS 4
#define ODIM  64
#define HO    256            // HEADS*ODIM
#define MROWS (BATCH*NNODE)  // 42336
#define SGH   (BATCH*HEADS*NNODE)  // 169344

typedef __attribute__((ext_vector_type(8))) short bf16x8;
typedef __attribute__((ext_vector_type(8))) unsigned short u16x8;
typedef __attribute__((ext_vector_type(4))) float f32x4;

// exact RNE f32->bf16 (known-good; do NOT replace with v_cvt_pk_bf16_f32 —
// R1 showed that instruction's rounding breaks the absmax check: 7.6e-2 vs 7.8e-3)
__device__ __forceinline__ ushort f2bf(float f) {
    unsigned u = __float_as_uint(f);
    unsigned r = (u + 0x7FFFu + ((u >> 16) & 1u)) >> 16;   // RNE
    return (ushort)r;
}
__device__ __forceinline__ float bf2f(ushort h) {
    return __uint_as_float(((unsigned)h) << 16);
}
// fast sigmoid: v_mul + v_exp + v_add + v_rcp (kept from R2: VALUBusy 31->20%)
__device__ __forceinline__ float fsigmoid(float x) {
    float e = __expf(-x);
    return __builtin_amdgcn_rcpf(1.0f + e);
}

#define MSTR 264   // LDS row stride (256 + 8 pad)

// weight fragment fetch from pre-shuffled layout (wg/lane from scope)
#define FRAG(src, jn, k0t) \
    (*(const bf16x8*)((src) + ((((wg * 4 + (jn)) * 8 + (k0t)) << 9)) + lane * 8))

// ---------------------------------------------------------------------------
// Fused double-GEMM — unchanged from R6 (stable ~44-47 µs).
__global__ __launch_bounds__(256)
void fused_gemm(const float* __restrict__ x, const ushort* __restrict__ wshuf,
                const ushort* __restrict__ kshuf, const float* __restrict__ bmlp,
                float* __restrict__ zbacc, ushort* __restrict__ xp0,
                const float* __restrict__ askv, const float* __restrict__ ankv,
                float* __restrict__ s0, float* __restrict__ ng0)
{
    __shared__ __attribute__((aligned(16))) ushort AsMs[32 * MSTR]; // x bf16 / mlp bf16
    __shared__ float cs_lds[256];   // per-block mlp col sums (deferred atomic)

    const int t    = threadIdx.x;
    const int lane = t & 63;
    const int wg   = t >> 6;            // 0..3 col-group / head
    const int lr   = lane & 15, kq = lane >> 4;
    const int rb   = blockIdx.x;        // 0..12 row-block within batch
    const int b    = blockIdx.y;
    const int row0 = rb * 32;
    const long gbase = (long)b * NNODE;

    // 2-deep prefetch of phase-1 weight fragments (no LDS dep; overlaps staging)
    bf16x8 wreg[2][4];
    #pragma unroll
    for (int jn = 0; jn < 4; ++jn) {
        wreg[0][jn] = FRAG(wshuf, jn, 0);
        wreg[1][jn] = FRAG(wshuf, jn, 1);
    }

    // ---- stage 32x256 x block (fp32 -> bf16), coalesced ----
    {
        const float* xb = x + (gbase + row0) * 256;
        #pragma unroll
        for (int j = 0; j < 8; ++j) {
            int e4  = t + j * 256;
            int row = e4 >> 6;
            int col = (e4 & 63) * 4;
            float4 v = (row0 + row < NNODE)
                ? *(const float4*)(xb + (long)row * 256 + col)
                : make_float4(0.f, 0.f, 0.f, 0.f);
            *(ushort4*)&AsMs[row * MSTR + col] =
                make_ushort4(f2bf(v.x), f2bf(v.y), f2bf(v.z), f2bf(v.w));
        }
    }
    __syncthreads();                        // barrier 1

    f32x4 acc[4][2] = {};   // [jn][imL]

    // ---------------- phase 1: mlp = sigmoid(x @ W + b) ----------------
    {
        #pragma unroll
        for (int k0t = 0; k0t < 8; ++k0t) {
            bf16x8 xf0 = *(const bf16x8*)&AsMs[lr * MSTR + k0t * 32 + kq * 8];
            bf16x8 xf1 = *(const bf16x8*)&AsMs[(16 + lr) * MSTR + k0t * 32 + kq * 8];
            #pragma unroll
            for (int jn = 0; jn < 4; ++jn) {
                acc[jn][0] = __builtin_amdgcn_mfma_f32_16x16x32_bf16(
                    wreg[k0t & 1][jn], xf0, acc[jn][0], 0, 0, 0);
                acc[jn][1] = __builtin_amdgcn_mfma_f32_16x16x32_bf16(
                    wreg[k0t & 1][jn], xf1, acc[jn][1], 0, 0, 0);
            }
            if (k0t < 6) {
                #pragma unroll
                for (int jn = 0; jn < 4; ++jn)
                    wreg[k0t & 1][jn] = FRAG(wshuf, jn, k0t + 2);
            }
        }
    }

    // prefetch phase-2 buffer 0 (overlaps epilogue 1; drained at barrier 2)
    bf16x8 kreg[2][4];
    #pragma unroll
    for (int jn = 0; jn < 4; ++jn) kreg[0][jn] = FRAG(kshuf, jn, 0);

    __syncthreads();                        // barrier 2

    // ---- epilogue 1: sigmoid -> Ms (aliases x); col sums -> cs_lds ----
    {
        float4 bi[4];
        #pragma unroll
        for (int jn = 0; jn < 4; ++jn)
            bi[jn] = *(const float4*)(bmlp + 64 * wg + 16 * jn + 4 * kq);
        float cs[4][4] = {};
        #pragma unroll
        for (int imL = 0; imL < 2; ++imL) {
            const int r_ = 16 * imL + lr;
            const bool ok = row0 + r_ < NNODE;
            #pragma unroll
            for (int jn = 0; jn < 4; ++jn) {
                float v[4];
                v[0] = fsigmoid(acc[jn][imL][0] + bi[jn].x);
                v[1] = fsigmoid(acc[jn][imL][1] + bi[jn].y);
                v[2] = fsigmoid(acc[jn][imL][2] + bi[jn].z);
                v[3] = fsigmoid(acc[jn][imL][3] + bi[jn].w);
                *(ushort4*)&AsMs[r_ * MSTR + 64 * wg + 16 * jn + 4 * kq] =
                    make_ushort4(f2bf(v[0]), f2bf(v[1]), f2bf(v[2]), f2bf(v[3]));
                if (ok) {
                    cs[jn][0] += v[0]; cs[jn][1] += v[1];
                    cs[jn][2] += v[2]; cs[jn][3] += v[3];
                }
            }
        }
        #pragma unroll
        for (int jn = 0; jn < 4; ++jn)
            #pragma unroll
            for (int r = 0; r < 4; ++r) {
                float v = cs[jn][r];
                v += __shfl_xor(v, 1, 64);
                v += __shfl_xor(v, 2, 64);
                v += __shfl_xor(v, 4, 64);
                v += __shfl_xor(v, 8, 64);
                if (lr == 0)
                    cs_lds[64 * wg + 16 * jn + 4 * kq + r] = v;
            }
    }
    __syncthreads();                        // barrier 3

    // ---------------- phase 2: xp0 = 0.2 * (Ms @ K^T) ----------------
    #pragma unroll
    for (int jn = 0; jn < 4; ++jn)
        #pragma unroll
        for (int imL = 0; imL < 2; ++imL)
            acc[jn][imL] = f32x4{0.f, 0.f, 0.f, 0.f};

    // prefetch phase-2 buffer 1 (covered by k0t=0's LDS reads + MFMAs)
    #pragma unroll
    for (int jn = 0; jn < 4; ++jn) kreg[1][jn] = FRAG(kshuf, jn, 1);

    {
        #pragma unroll
        for (int k0t = 0; k0t < 8; ++k0t) {
            bf16x8 xf0 = *(const bf16x8*)&AsMs[lr * MSTR + k0t * 32 + kq * 8];
            bf16x8 xf1 = *(const bf16x8*)&AsMs[(16 + lr) * MSTR + k0t * 32 + kq * 8];
            #pragma unroll
            for (int jn = 0; jn < 4; ++jn) {
                acc[jn][0] = __builtin_amdgcn_mfma_f32_16x16x32_bf16(
                    kreg[k0t & 1][jn], xf0, acc[jn][0], 0, 0, 0);
                acc[jn][1] = __builtin_amdgcn_mfma_f32_16x16x32_bf16(
                    kreg[k0t & 1][jn], xf1, acc[jn][1], 0, 0, 0);
            }
            if (k0t < 6) {
                #pragma unroll
                for (int jn = 0; jn < 4; ++jn)
                    kreg[k0t & 1][jn] = FRAG(kshuf, jn, k0t + 2);
            }
        }
    }

    // ---- epilogue 2: xp0 stores + fused s0/ng0 projections ----
    {
        const int h = wg;
        float askr[4][4], ankr[4][4];
        #pragma unroll
        for (int jn = 0; jn < 4; ++jn)
            #pragma unroll
            for (int r = 0; r < 4; ++r) {
                int o = 16 * jn + 4 * kq + r;
                askr[jn][r] = askv[o * HEADS + h];
                ankr[jn][r] = ankv[o * HEADS + h];
            }
        #pragma unroll
        for (int imL = 0; imL < 2; ++imL) {
            const int r_ = 16 * imL + lr;
            const int lrow = row0 + r_;
            const bool ok = lrow < NNODE;
            float ps = 0.0f, pn = 0.0f;
            if (ok) {
                ushort* dst = xp0 + (gbase + lrow) * 256 + 64 * h + 4 * kq;
                #pragma unroll
                for (int jn = 0; jn < 4; ++jn) {
                    float v0 = 0.2f * acc[jn][imL][0];
                    float v1 = 0.2f * acc[jn][imL][1];
                    float v2 = 0.2f * acc[jn][imL][2];
                    float v3 = 0.2f * acc[jn][imL][3];
                    *(ushort4*)(dst + 16 * jn) =
                        make_ushort4(f2bf(v0), f2bf(v1), f2bf(v2), f2bf(v3));
                    ps += v0 * askr[jn][0] + v1 * askr[jn][1] +
                          v2 * askr[jn][2] + v3 * askr[jn][3];
                    pn += v0 * ankr[jn][0] + v1 * ankr[jn][1] +
                          v2 * ankr[jn][2] + v3 * ankr[jn][3];
                }
            }
            ps += __shfl_xor(ps, 16, 64);
            ps += __shfl_xor(ps, 32, 64);
            pn += __shfl_xor(pn, 16, 64);
            pn += __shfl_xor(pn, 32, 64);
            if (ok && kq == 0) {
                long si = ((long)b * HEADS + h) * NNODE + lrow;
                s0[si]  = ps;
                ng0[si] = pn;
            }
        }
    }

    // deferred zbacc accumulation (cs_lds complete since barrier 3)
    atomicAdd(&zbacc[b * 256 + t], cs_lds[t]);
}

// ---------------------------------------------------------------------------
// Weight transpose + bf16 + MFMA-fragment shuffle; also zeroes zbacc.
__global__ __launch_bounds__(256)
void wcvt(const float* __restrict__ w_mlp, const float* __restrict__ kern,
          ushort* __restrict__ wshuf, ushort* __restrict__ kshuf,
          float* __restrict__ zbacc)
{
    if (blockIdx.x < BATCH)
        zbacc[blockIdx.x * 256 + threadIdx.x] = 0.0f;
    long idx = (long)(blockIdx.x & 255) * 256 + threadIdx.x;   // 0..65535
    const float* src = (blockIdx.x < 256) ? w_mlp : kern;
    ushort* dst = (blockIdx.x < 256) ? wshuf : kshuf;
    int e    = idx & 7;
    int lane = (int)(idx >> 3) & 63;
    int k0t  = (int)(idx >> 9) & 7;
    int jn   = (int)(idx >> 12) & 3;
    int g    = (int)(idx >> 14);
    int n = 64 * g + 16 * jn + (lane & 15);
    int k = 32 * k0t + (lane >> 4) * 8 + e;
    dst[idx] = f2bf(src[(long)k * 256 + n]);
}

// ---------------------------------------------------------------------------
// attn_fused — R14: grid (2, 432) = 864 blocks; each block replicates the
// full stats (deterministic -> both halves compute identical g1s/g2s/tls)
// and runs only 2 of the 4 column passes. Rationale: R10 (78.8 KB LDS) and
// R12 (62.4 KB) both measured ~53% occupancy -> LDS never was the limiter;
// 432 blocks / 256 CUs is (176 CUs x 2 serial + 80 x 1), wall = 2 chains of
// (S + 4P). Splitting gives wall = 2 x (S + 2P). out written once per
// element (disjoint columns) -> bit-identical.
#define NP  (NNODE + 1)
__global__ __launch_bounds__(1024)
void attn_fused(const float* __restrict__ s0, const float* __restrict__ ng0,
                const float* __restrict__ zbacc, const float* __restrict__ kern,
                const float* __restrict__ askv, const float* __restrict__ ankv,
                const ushort* __restrict__ xp, const float* __restrict__ bias,
                float* __restrict__ out)
{
    __shared__ float  pool1[16 * NP];   // passes: Vs   | pre: key/perm/zsh/partK
    __shared__ float  pool2[16 * NP];   // passes: S1   | pre: D1/D2
    __shared__ float  CT[64][17];       // S1 cross-chunk (suffix)
    __shared__ float  CT2[64][17];      // S2 cross-chunk (prefix)
    __shared__ float  w1[NNODE], w2[NNODE];
    __shared__ float  g1s[NNODE], g2s[NNODE];
    __shared__ ushort tls[NNODE];
    __shared__ float  biasl[64];
    __shared__ float  wsumA[8], wsumB[8];
    __shared__ float  scs[2];

    float* const key   = pool1;                 // [512]
    int*   const perm  = (int*)(pool1 + 512);   // [512]
    float* const zsh   = pool1 + 1024;          // [256]
    float* const partK = pool1 + 1280;          // [16][64]
    float* const D1    = pool2;                 // [NNODE+1]
    float* const D2    = pool2 + 400;           // [NNODE+1]
    float* const Vs    = pool1;
    float* const S1    = pool2;

    const int t    = threadIdx.x;
    const int half = blockIdx.x;        // 0: passes 0-1, 1: passes 2-3
    const int bh   = blockIdx.y;
    const int b  = bh >> 2, h = bh & 3;
    const long base = (long)bh * NNODE;
    const int ln = t & 63, w = t >> 6;  // w in 0..15

    // ---- phase 0: zbK fold -> sc/ngc + biasl (all 16 waves) ----
    if (t < IDIM) zsh[t] = zbacc[b * 256 + t] * (0.8f / (float)NNODE);
    __syncthreads();
    {
        float p = 0.0f;                 // chunk w: k = w*16..w*16+15, col ln
        #pragma unroll
        for (int kk = 0; kk < 16; ++kk) {
            int k = w * 16 + kk;
            p = fmaf(zsh[k], kern[(long)k * HO + h * 64 + ln], p);
        }
        partK[w * 64 + ln] = p;
    }
    __syncthreads();
    if (t < 64) {
        float zk = 0.0f;
        #pragma unroll
        for (int kc = 0; kc < 16; ++kc) zk += partK[kc * 64 + t];
        biasl[t] = bias[h * 64 + t] + zk;
        float ps = zk * askv[t * HEADS + h];
        float pn = zk * ankv[t * HEADS + h];
        #pragma unroll
        for (int off = 32; off; off >>= 1) {
            ps += __shfl_down(ps, off, 64);
            pn += __shfl_down(pn, off, 64);
        }
        if (t == 0) { scs[0] = ps; scs[1] = pn; }
    }
    __syncthreads();
    const float sc = scs[0], ngc = scs[1];

    // ---- phase 1: register bitonic sort over t<512 (barriers uniform) ----
    float rk = (t < NNODE) ? (ng0[base + t] + ngc) : FLT_MAX;
    int   rp = t;

    for (int k = 2; k <= 512; k <<= 1) {
        for (int j = k >> 1; j > 0; j >>= 1) {
            if (j >= 64) {
                __syncthreads();
                if (t < 512) { key[t] = rk; perm[t] = rp; }
                __syncthreads();
                if (t < 512) {
                    const bool dir = ((t & k) == 0);
                    const bool lower = ((t & j) == 0);
                    float ok_ = key[t ^ j];
                    int   op  = perm[t ^ j];
                    const bool sw = lower ? ((rk > ok_) == dir)
                                          : ((ok_ > rk) == dir);
                    if (sw) { rk = ok_; rp = op; }
                }
            } else {
                if (t < 512) {
                    const bool dir = ((t & k) == 0);
                    const bool lower = ((t & j) == 0);
                    float ok_ = __shfl_xor(rk, j, 64);
                    int   op  = __shfl_xor(rp, j, 64);
                    const bool sw = lower ? ((rk > ok_) == dir)
                                          : ((ok_ > rk) == dir);
                    if (sw) { rk = ok_; rp = op; }
                }
            }
        }
    }
    __syncthreads();
    if (t < 512) { key[t] = rk; perm[t] = rp; }   // publish sorted keys/perm

    // ---- phase 2: weights + wave-shfl scans (t<512) ----
    const float w1v = (t < NNODE) ? __expf(rk) : 0.0f;
    const float w2v = (t < NNODE) ? __expf(0.2f * rk) : 0.0f;
    if (t < NNODE) { w1[t] = w1v; w2[t] = w2v; }

    float v1 = w1v, v2 = 0.0f;
    if (t < 512) {
        // D1: inclusive suffix sum of w1v
        #pragma unroll
        for (int s = 1; s < 64; s <<= 1) {
            float tmp = __shfl_down(v1, s, 64);
            if (ln + s < 64) v1 += tmp;
        }
        // D2: exclusive prefix sum of w2v
        v2 = (ln >= 1) ? __shfl_up(w2v, 1, 64) : 0.0f;
        #pragma unroll
        for (int s = 1; s < 64; s <<= 1) {
            float tmp = __shfl_up(v2, s, 64);
            if (ln >= s) v2 += tmp;
        }
        const float wt2 = __shfl(v2, 63, 64) + __shfl(w2v, 63, 64);
        if (ln == 0) { wsumA[w] = v1; wsumB[w] = wt2; }
    }
    __syncthreads();

    // issue first-pass gather loads now (perm published; perm/key regions of
    // pool1 are dead after this + the binary search below)
    u16x8 raw;
    const bool gt = (t < NNODE * 2);
    const int gj = t >> 1, gq = (t & 1) * 8;
    int grow = 0;
    if (gt) {
        grow = perm[gj];
        raw = *(const u16x8*)(xp + ((long)b * NNODE + grow) * HO +
                              h * 64 + (half * 2) * 16 + gq);
    }

    if (t < 512) {
        float off1 = 0.0f, off2 = 0.0f;
        for (int ww = w + 1; ww < 8; ++ww) off1 += wsumA[ww];
        for (int ww = 0; ww < w; ++ww)     off2 += wsumB[ww];
        if (t < NNODE) {
            D1[t] = v1 + off1;
            D2[t] = v2 + off2;
        }
        if (t == 0) {
            D1[NNODE] = 0.0f;
            float tot = 0.0f;
            #pragma unroll
            for (int ww = 0; ww < 8; ++ww) tot += wsumB[ww];
            D2[NNODE] = tot;
        }
    }
    __syncthreads();

    if (t < NNODE) {
        float sn = s0[base + t] + sc;
        float negs = -sn;
        int lo = 0, hi = NNODE;
        while (lo < hi) {
            int mid = (lo + hi) >> 1;
            if (key[mid] < negs) lo = mid + 1; else hi = mid;
        }
        float e1 = __expf(sn), e2 = __expf(0.2f * sn);
        float inv = __builtin_amdgcn_rcpf(e1 * D1[lo] + e2 * D2[lo]);
        g1s[t] = e1 * inv;
        g2s[t] = e2 * inv;
        tls[t] = (ushort)lo;
    }
    __syncthreads();    // after this barrier pool1/pool2 pre-pass data is dead

    // ---- phase 3: 2 passes x 16 o-cols (this block's og-half) ----
    const int c = t >> 4, o = t & 15;
    for (int p = 0; p < 2; ++p) {
        const int og2 = half * 2 + p;
        const int c0 = h * 64 + og2 * 16;

        // scatter prefetched gather into column-major LDS (overwrites pool1)
        if (gt) {
            #pragma unroll
            for (int oo = 0; oo < 8; ++oo) Vs[(gq + oo) * NP + gj] = bf2f(raw[oo]);
        }
        __syncthreads();                                    // B1
        // issue next pass's loads (consumed after the emit barrier)
        if (p == 0 && gt)
            raw = *(const u16x8*)(xp + ((long)b * NNODE + grow) * HO +
                                  h * 64 + (og2 + 1) * 16 + gq);

        // merged chunk scans: S1 suffix then S2 prefix — same thread owns
        // the same (c,o) elements, so no barrier between them
        {
            float a1 = 0.0f;
            #pragma unroll
            for (int jj = 6; jj >= 0; --jj) {
                int j = c * 7 + jj;
                if (j < NNODE) {
                    a1 = fmaf(w1[j], Vs[o * NP + j], a1);
                    S1[o * NP + j] = a1;
                }
            }
            CT[c][o] = a1;
            float a2 = 0.0f;
            #pragma unroll
            for (int jj = 0; jj < 7; ++jj) {
                int j = c * 7 + jj;
                if (j < NNODE) {
                    float tmp = Vs[o * NP + j];
                    Vs[o * NP + j] = a2;
                    a2 = fmaf(w2[j], tmp, a2);
                }
            }
            CT2[c][o] = a2;
        }
        __syncthreads();                                    // B2
        // merged wave scans: CT suffix (shfl_down) + CT2 prefix (shfl_up)
        {
            float vA = CT[ln][w];
            float vB = CT2[ln][w];
            #pragma unroll
            for (int s = 1; s < 64; s <<= 1) {
                float tA = __shfl_down(vA, s, 64);
                float tB = __shfl_up(vB, s, 64);
                if (ln + s < 64) vA += tA;
                if (ln >= s)     vB += tB;
            }
            CT[ln][w] = vA;
            CT2[ln][w] = vB;
        }
        __syncthreads();                                    // B3
        // merged offset applies + boundary cells
        {
            float offA = (c < 63) ? CT[c + 1][o] : 0.0f;
            float offB = (c > 0) ? CT2[c - 1][o] : 0.0f;
            #pragma unroll
            for (int jj = 0; jj < 7; ++jj) {
                int j = c * 7 + jj;
                if (j < NNODE) {
                    S1[o * NP + j] += offA;
                    Vs[o * NP + j] += offB;
                }
            }
            if (c == 0)  S1[o * NP + NNODE] = 0.0f;
            if (c == 63) Vs[o * NP + NNODE] = CT2[63][o];
        }
        __syncthreads();                                    // B4

        // emit: nontemporal f32x4 (ext_vector) per (row, col-quad)
        for (int idx = t; idx < NNODE * 4; idx += 1024) {
            int n = idx >> 2, q = (idx & 3) * 4;
            int tt = tls[n];
            float g1 = g1s[n], g2 = g2s[n];
            f32x4 r;
            #pragma unroll
            for (int rr = 0; rr < 4; ++rr) {
                int oo = q + rr;
                float v = g1 * S1[oo * NP + tt] + g2 * Vs[oo * NP + tt] +
                          biasl[og2 * 16 + oo];
                r[rr] = (v > 0.0f) ? v : (__expf(v) - 1.0f);
            }
            __builtin_nontemporal_store(
                r, (f32x4*)(out + ((long)b * NNODE + n) * HO + c0 + q));
        }
        __syncthreads();                                    // B5
    }
}

extern "C" void kernel_launch(void* const* d_in, const int* in_sizes, int n_in,
                              void* d_out, int out_size, void* d_ws, size_t ws_size,
                              hipStream_t stream) {
    const float* x     = (const float*)d_in[0];   // [108,392,256]
    const float* w_mlp = (const float*)d_in[2];   // [256,256]
    const float* b_mlp = (const float*)d_in[3];   // [256]
    const float* kern  = (const float*)d_in[4];   // [256,4,64] == [256,256]
    const float* ask   = (const float*)d_in[5];   // [64,4,1]
    const float* ank   = (const float*)d_in[6];   // [64,4,1]
    const float* bias  = (const float*)d_in[7];   // [256]
    float* out = (float*)d_out;

    const long TENS = (long)MROWS * IDIM;         // 10,838,016
    float*  s0    = (float*)d_ws;                 // [B,H,N]
    float*  ng0   = s0 + SGH;
    float*  zbacc = ng0 + SGH;                    // [B,256] atomically built
    ushort* xp_bf = (ushort*)(zbacc + (long)BATCH * IDIM);  // [B,N,H*O] bf16
    ushort* wshuf = xp_bf + TENS;                 // [65536] frag-order w_mlp
    ushort* kshuf = wshuf + 65536;                // [65536] frag-order kernel

    dim3 blk(256);

    // 0) weight shuffle + zbacc zeroing (fused)
    wcvt<<<dim3(512), blk, 0, stream>>>(w_mlp, kern, wshuf, kshuf, zbacc);

    // 1) fused: mlp(sigmoid, LDS-only) -> col-sums -> xp0 + s0/ng0
    fused_gemm<<<dim3(13, BATCH), dim3(256), 0, stream>>>(
        x, wshuf, kshuf, b_mlp, zbacc, xp_bf, ask, ank, s0, ng0);

    // 2) fused attention, split grid: 2 blocks per (b,h), each = stats + 2 passes
    attn_fused<<<dim3(2, BATCH * HEADS), dim3(1024), 0, stream>>>(
        s0, ng0, zbacc, kern, ask, ank, xp_bf, bias, out);
}

// Round 15
// 174.683 us; speedup vs baseline: 1.0453x; 1.0453x over previous
//
#include <hip/hip_runtime.h>
#include <hip/hip_bf16.h>
#include <math.h>
#include <float.h>

// Problem constants (fixed by setup_inputs)
#define BATCH 108
#define NNODE 392
#define IDIM  256
#define HEADS 4
#define ODIM  64
#define HO    256            // HEADS*ODIM
#define MROWS (BATCH*NNODE)  // 42336
#define SGH   (BATCH*HEADS*NNODE)  // 169344

typedef __attribute__((ext_vector_type(8))) short bf16x8;
typedef __attribute__((ext_vector_type(8))) unsigned short u16x8;
typedef __attribute__((ext_vector_type(4))) float f32x4;

// exact RNE f32->bf16 (known-good; do NOT replace with v_cvt_pk_bf16_f32 —
// R1 showed that instruction's rounding breaks the absmax check: 7.6e-2 vs 7.8e-3)
__device__ __forceinline__ ushort f2bf(float f) {
    unsigned u = __float_as_uint(f);
    unsigned r = (u + 0x7FFFu + ((u >> 16) & 1u)) >> 16;   // RNE
    return (ushort)r;
}
__device__ __forceinline__ float bf2f(ushort h) {
    return __uint_as_float(((unsigned)h) << 16);
}
// fast sigmoid: v_mul + v_exp + v_add + v_rcp (kept from R2: VALUBusy 31->20%)
__device__ __forceinline__ float fsigmoid(float x) {
    float e = __expf(-x);
    return __builtin_amdgcn_rcpf(1.0f + e);
}

#define MSTR 264   // LDS row stride (256 + 8 pad)

// weight fragment fetch from pre-shuffled layout (wg/lane from scope)
#define FRAG(src, jn, k0t) \
    (*(const bf16x8*)((src) + ((((wg * 4 + (jn)) * 8 + (k0t)) << 9)) + lane * 8))

// ---------------------------------------------------------------------------
// Fused double-GEMM — unchanged from R6 (stable ~44-47 µs).
__global__ __launch_bounds__(256)
void fused_gemm(const float* __restrict__ x, const ushort* __restrict__ wshuf,
                const ushort* __restrict__ kshuf, const float* __restrict__ bmlp,
                float* __restrict__ zbacc, ushort* __restrict__ xp0,
                const float* __restrict__ askv, const float* __restrict__ ankv,
                float* __restrict__ s0, float* __restrict__ ng0)
{
    __shared__ __attribute__((aligned(16))) ushort AsMs[32 * MSTR]; // x bf16 / mlp bf16
    __shared__ float cs_lds[256];   // per-block mlp col sums (deferred atomic)

    const int t    = threadIdx.x;
    const int lane = t & 63;
    const int wg   = t >> 6;            // 0..3 col-group / head
    const int lr   = lane & 15, kq = lane >> 4;
    const int rb   = blockIdx.x;        // 0..12 row-block within batch
    const int b    = blockIdx.y;
    const int row0 = rb * 32;
    const long gbase = (long)b * NNODE;

    // 2-deep prefetch of phase-1 weight fragments (no LDS dep; overlaps staging)
    bf16x8 wreg[2][4];
    #pragma unroll
    for (int jn = 0; jn < 4; ++jn) {
        wreg[0][jn] = FRAG(wshuf, jn, 0);
        wreg[1][jn] = FRAG(wshuf, jn, 1);
    }

    // ---- stage 32x256 x block (fp32 -> bf16), coalesced ----
    {
        const float* xb = x + (gbase + row0) * 256;
        #pragma unroll
        for (int j = 0; j < 8; ++j) {
            int e4  = t + j * 256;
            int row = e4 >> 6;
            int col = (e4 & 63) * 4;
            float4 v = (row0 + row < NNODE)
                ? *(const float4*)(xb + (long)row * 256 + col)
                : make_float4(0.f, 0.f, 0.f, 0.f);
            *(ushort4*)&AsMs[row * MSTR + col] =
                make_ushort4(f2bf(v.x), f2bf(v.y), f2bf(v.z), f2bf(v.w));
        }
    }
    __syncthreads();                        // barrier 1

    f32x4 acc[4][2] = {};   // [jn][imL]

    // ---------------- phase 1: mlp = sigmoid(x @ W + b) ----------------
    {
        #pragma unroll
        for (int k0t = 0; k0t < 8; ++k0t) {
            bf16x8 xf0 = *(const bf16x8*)&AsMs[lr * MSTR + k0t * 32 + kq * 8];
            bf16x8 xf1 = *(const bf16x8*)&AsMs[(16 + lr) * MSTR + k0t * 32 + kq * 8];
            #pragma unroll
            for (int jn = 0; jn < 4; ++jn) {
                acc[jn][0] = __builtin_amdgcn_mfma_f32_16x16x32_bf16(
                    wreg[k0t & 1][jn], xf0, acc[jn][0], 0, 0, 0);
                acc[jn][1] = __builtin_amdgcn_mfma_f32_16x16x32_bf16(
                    wreg[k0t & 1][jn], xf1, acc[jn][1], 0, 0, 0);
            }
            if (k0t < 6) {
                #pragma unroll
                for (int jn = 0; jn < 4; ++jn)
                    wreg[k0t & 1][jn] = FRAG(wshuf, jn, k0t + 2);
            }
        }
    }

    // prefetch phase-2 buffer 0 (overlaps epilogue 1; drained at barrier 2)
    bf16x8 kreg[2][4];
    #pragma unroll
    for (int jn = 0; jn < 4; ++jn) kreg[0][jn] = FRAG(kshuf, jn, 0);

    __syncthreads();                        // barrier 2

    // ---- epilogue 1: sigmoid -> Ms (aliases x); col sums -> cs_lds ----
    {
        float4 bi[4];
        #pragma unroll
        for (int jn = 0; jn < 4; ++jn)
            bi[jn] = *(const float4*)(bmlp + 64 * wg + 16 * jn + 4 * kq);
        float cs[4][4] = {};
        #pragma unroll
        for (int imL = 0; imL < 2; ++imL) {
            const int r_ = 16 * imL + lr;
            const bool ok = row0 + r_ < NNODE;
            #pragma unroll
            for (int jn = 0; jn < 4; ++jn) {
                float v[4];
                v[0] = fsigmoid(acc[jn][imL][0] + bi[jn].x);
                v[1] = fsigmoid(acc[jn][imL][1] + bi[jn].y);
                v[2] = fsigmoid(acc[jn][imL][2] + bi[jn].z);
                v[3] = fsigmoid(acc[jn][imL][3] + bi[jn].w);
                *(ushort4*)&AsMs[r_ * MSTR + 64 * wg + 16 * jn + 4 * kq] =
                    make_ushort4(f2bf(v[0]), f2bf(v[1]), f2bf(v[2]), f2bf(v[3]));
                if (ok) {
                    cs[jn][0] += v[0]; cs[jn][1] += v[1];
                    cs[jn][2] += v[2]; cs[jn][3] += v[3];
                }
            }
        }
        #pragma unroll
        for (int jn = 0; jn < 4; ++jn)
            #pragma unroll
            for (int r = 0; r < 4; ++r) {
                float v = cs[jn][r];
                v += __shfl_xor(v, 1, 64);
                v += __shfl_xor(v, 2, 64);
                v += __shfl_xor(v, 4, 64);
                v += __shfl_xor(v, 8, 64);
                if (lr == 0)
                    cs_lds[64 * wg + 16 * jn + 4 * kq + r] = v;
            }
    }
    __syncthreads();                        // barrier 3

    // ---------------- phase 2: xp0 = 0.2 * (Ms @ K^T) ----------------
    #pragma unroll
    for (int jn = 0; jn < 4; ++jn)
        #pragma unroll
        for (int imL = 0; imL < 2; ++imL)
            acc[jn][imL] = f32x4{0.f, 0.f, 0.f, 0.f};

    // prefetch phase-2 buffer 1 (covered by k0t=0's LDS reads + MFMAs)
    #pragma unroll
    for (int jn = 0; jn < 4; ++jn) kreg[1][jn] = FRAG(kshuf, jn, 1);

    {
        #pragma unroll
        for (int k0t = 0; k0t < 8; ++k0t) {
            bf16x8 xf0 = *(const bf16x8*)&AsMs[lr * MSTR + k0t * 32 + kq * 8];
            bf16x8 xf1 = *(const bf16x8*)&AsMs[(16 + lr) * MSTR + k0t * 32 + kq * 8];
            #pragma unroll
            for (int jn = 0; jn < 4; ++jn) {
                acc[jn][0] = __builtin_amdgcn_mfma_f32_16x16x32_bf16(
                    kreg[k0t & 1][jn], xf0, acc[jn][0], 0, 0, 0);
                acc[jn][1] = __builtin_amdgcn_mfma_f32_16x16x32_bf16(
                    kreg[k0t & 1][jn], xf1, acc[jn][1], 0, 0, 0);
            }
            if (k0t < 6) {
                #pragma unroll
                for (int jn = 0; jn < 4; ++jn)
                    kreg[k0t & 1][jn] = FRAG(kshuf, jn, k0t + 2);
            }
        }
    }

    // ---- epilogue 2: xp0 stores + fused s0/ng0 projections ----
    {
        const int h = wg;
        float askr[4][4], ankr[4][4];
        #pragma unroll
        for (int jn = 0; jn < 4; ++jn)
            #pragma unroll
            for (int r = 0; r < 4; ++r) {
                int o = 16 * jn + 4 * kq + r;
                askr[jn][r] = askv[o * HEADS + h];
                ankr[jn][r] = ankv[o * HEADS + h];
            }
        #pragma unroll
        for (int imL = 0; imL < 2; ++imL) {
            const int r_ = 16 * imL + lr;
            const int lrow = row0 + r_;
            const bool ok = lrow < NNODE;
            float ps = 0.0f, pn = 0.0f;
            if (ok) {
                ushort* dst = xp0 + (gbase + lrow) * 256 + 64 * h + 4 * kq;
                #pragma unroll
                for (int jn = 0; jn < 4; ++jn) {
                    float v0 = 0.2f * acc[jn][imL][0];
                    float v1 = 0.2f * acc[jn][imL][1];
                    float v2 = 0.2f * acc[jn][imL][2];
                    float v3 = 0.2f * acc[jn][imL][3];
                    *(ushort4*)(dst + 16 * jn) =
                        make_ushort4(f2bf(v0), f2bf(v1), f2bf(v2), f2bf(v3));
                    ps += v0 * askr[jn][0] + v1 * askr[jn][1] +
                          v2 * askr[jn][2] + v3 * askr[jn][3];
                    pn += v0 * ankr[jn][0] + v1 * ankr[jn][1] +
                          v2 * ankr[jn][2] + v3 * ankr[jn][3];
                }
            }
            ps += __shfl_xor(ps, 16, 64);
            ps += __shfl_xor(ps, 32, 64);
            pn += __shfl_xor(pn, 16, 64);
            pn += __shfl_xor(pn, 32, 64);
            if (ok && kq == 0) {
                long si = ((long)b * HEADS + h) * NNODE + lrow;
                s0[si]  = ps;
                ng0[si] = pn;
            }
        }
    }

    // deferred zbacc accumulation (cs_lds complete since barrier 3)
    atomicAdd(&zbacc[b * 256 + t], cs_lds[t]);
}

// ---------------------------------------------------------------------------
// Weight transpose + bf16 + MFMA-fragment shuffle; also zeroes zbacc.
__global__ __launch_bounds__(256)
void wcvt(const float* __restrict__ w_mlp, const float* __restrict__ kern,
          ushort* __restrict__ wshuf, ushort* __restrict__ kshuf,
          float* __restrict__ zbacc)
{
    if (blockIdx.x < BATCH)
        zbacc[blockIdx.x * 256 + threadIdx.x] = 0.0f;
    long idx = (long)(blockIdx.x & 255) * 256 + threadIdx.x;   // 0..65535
    const float* src = (blockIdx.x < 256) ? w_mlp : kern;
    ushort* dst = (blockIdx.x < 256) ? wshuf : kshuf;
    int e    = idx & 7;
    int lane = (int)(idx >> 3) & 63;
    int k0t  = (int)(idx >> 9) & 7;
    int jn   = (int)(idx >> 12) & 3;
    int g    = (int)(idx >> 14);
    int n = 64 * g + 16 * jn + (lane & 15);
    int k = 32 * k0t + (lane >> 4) * 8 + e;
    dst[idx] = f2bf(src[(long)k * 256 + n]);
}

// ---------------------------------------------------------------------------
// attn_stats — R15: stats computed ONCE per (b,h) (R14 showed replicating it
// in the split scan blocks costs ~1.7x stats work = +13 µs). This is R7's
// proven kernel (zbK fold + register bitonic sort + wave-shfl D1/D2 scans +
// thresholds), 512 thr / ~14 KB LDS -> high occupancy, plus a biasG write so
// the scan kernel need not redo the fold.
__global__ __launch_bounds__(512)
void attn_stats(const float* __restrict__ s0, const float* __restrict__ ng0,
                const float* __restrict__ zbacc, const float* __restrict__ kern,
                const float* __restrict__ askv, const float* __restrict__ ankv,
                const float* __restrict__ bias, uint* __restrict__ ptG,
                float2* __restrict__ w12G, float2* __restrict__ g12G,
                float* __restrict__ biasG)
{
    __shared__ float key[512];
    __shared__ int   perm[512];
    __shared__ float w1[NNODE], w2[NNODE];
    __shared__ float D1[NNODE + 1], D2[NNODE + 1];
    __shared__ float zsh[IDIM];
    __shared__ float partK[8][64];
    __shared__ float wsumA[8], wsumB[8];
    __shared__ float scs[2];

    const int t = threadIdx.x;
    const int bh = blockIdx.x;
    const int b = bh >> 2, h = bh & 3;
    const long base = (long)bh * NNODE;
    const int ln = t & 63, w = t >> 6;

    // ---- zbK fold: sc/ngc + biasG ----
    if (t < IDIM) zsh[t] = zbacc[b * 256 + t] * (0.8f / (float)NNODE);
    __syncthreads();
    {
        float p = 0.0f;
        #pragma unroll
        for (int kk = 0; kk < 32; ++kk) {
            int k = w * 32 + kk;
            p = fmaf(zsh[k], kern[(long)k * HO + h * 64 + ln], p);
        }
        partK[w][ln] = p;
    }
    __syncthreads();
    if (t < 64) {
        float zk = 0.0f;
        #pragma unroll
        for (int kc = 0; kc < 8; ++kc) zk += partK[kc][t];
        biasG[bh * 64 + t] = bias[h * 64 + t] + zk;
        float ps = zk * askv[t * HEADS + h];
        float pn = zk * ankv[t * HEADS + h];
        #pragma unroll
        for (int off = 32; off; off >>= 1) {
            ps += __shfl_down(ps, off, 64);
            pn += __shfl_down(pn, off, 64);
        }
        if (t == 0) { scs[0] = ps; scs[1] = pn; }
    }
    __syncthreads();
    const float sc = scs[0], ngc = scs[1];

    // ---- register-resident bitonic sort (R5) ----
    float rk = (t < NNODE) ? (ng0[base + t] + ngc) : FLT_MAX;
    int   rp = t;

    for (int k = 2; k <= 512; k <<= 1) {
        for (int j = k >> 1; j > 0; j >>= 1) {
            const bool dir = ((t & k) == 0);
            const bool lower = ((t & j) == 0);
            float ok_; int op;
            if (j >= 64) {
                __syncthreads();
                key[t] = rk; perm[t] = rp;
                __syncthreads();
                ok_ = key[t ^ j];
                op  = perm[t ^ j];
            } else {
                ok_ = __shfl_xor(rk, j, 64);
                op  = __shfl_xor(rp, j, 64);
            }
            const bool sw = lower ? ((rk > ok_) == dir) : ((ok_ > rk) == dir);
            if (sw) { rk = ok_; rp = op; }
        }
    }
    __syncthreads();
    key[t] = rk; perm[t] = rp;

    // ---- weights + wave-shfl suffix/prefix scans ----
    const float w1v = (t < NNODE) ? __expf(rk) : 0.0f;
    const float w2v = (t < NNODE) ? __expf(0.2f * rk) : 0.0f;
    if (t < NNODE) { w1[t] = w1v; w2[t] = w2v; }

    float v1 = w1v;
    #pragma unroll
    for (int s = 1; s < 64; s <<= 1) {
        float tmp = __shfl_down(v1, s, 64);
        if (ln + s < 64) v1 += tmp;
    }
    float v2 = (ln >= 1) ? __shfl_up(w2v, 1, 64) : 0.0f;
    #pragma unroll
    for (int s = 1; s < 64; s <<= 1) {
        float tmp = __shfl_up(v2, s, 64);
        if (ln >= s) v2 += tmp;
    }
    const float wt2 = __shfl(v2, 63, 64) + __shfl(w2v, 63, 64);
    if (ln == 0) { wsumA[w] = v1; wsumB[w] = wt2; }
    __syncthreads();
    {
        float off1 = 0.0f, off2 = 0.0f;
        for (int ww = w + 1; ww < 8; ++ww) off1 += wsumA[ww];
        for (int ww = 0; ww < w; ++ww)     off2 += wsumB[ww];
        if (t < NNODE) {
            D1[t] = v1 + off1;
            D2[t] = v2 + off2;
        }
        if (t == 0) {
            D1[NNODE] = 0.0f;
            float tot = 0.0f;
            #pragma unroll
            for (int ww = 0; ww < 8; ++ww) tot += wsumB[ww];
            D2[NNODE] = tot;
        }
    }
    __syncthreads();

    if (t < NNODE) {
        float sn = s0[base + t] + sc;
        float negs = -sn;
        int lo = 0, hi = NNODE;
        while (lo < hi) {
            int mid = (lo + hi) >> 1;
            if (key[mid] < negs) lo = mid + 1; else hi = mid;
        }
        float e1 = __expf(sn), e2 = __expf(0.2f * sn);
        float inv = __builtin_amdgcn_rcpf(e1 * D1[lo] + e2 * D2[lo]);
        ptG[base + t]  = (uint)perm[t] | ((uint)lo << 16);
        g12G[base + t] = make_float2(e1 * inv, e2 * inv);
        w12G[base + t] = make_float2(w1[t], w2[t]);
    }
}

// ---------------------------------------------------------------------------
// attn_scan — R15: grid (2, 432); each block = 2 of the 4 column passes with
// R13's merged-barrier schedule (5 barriers/pass) + gather prefetch + nt
// stores. Metadata staged once from ptG/w12G/g12G/biasG (no sort here — the
// R14 lesson: replicated stats cost more than the HBM round-trip saves).
#define NP  (NNODE + 1)
__global__ __launch_bounds__(1024)
void attn_scan(const ushort* __restrict__ xp, const uint* __restrict__ ptG,
               const float2* __restrict__ w12G, const float2* __restrict__ g12G,
               const float* __restrict__ biasG, float* __restrict__ out)
{
    __shared__ float  Vs[16 * NP];
    __shared__ float  S1[16 * NP];
    __shared__ float  CT[64][17];
    __shared__ float  CT2[64][17];
    __shared__ float  w1[NNODE], w2[NNODE];
    __shared__ float  g1s[NNODE], g2s[NNODE];
    __shared__ ushort perms[NNODE], tls[NNODE];
    __shared__ float  biasl[64];

    const int t    = threadIdx.x;
    const int half = blockIdx.x;        // 0: passes 0-1, 1: passes 2-3
    const int bh   = blockIdx.y;
    const int b  = bh >> 2, h = bh & 3;
    const long base = (long)bh * NNODE;
    const int ln = t & 63, w = t >> 6;

    if (t < NNODE) {
        uint pt = ptG[base + t];
        perms[t] = (ushort)(pt & 0xFFFFu);
        tls[t]   = (ushort)(pt >> 16);
        float2 ww = w12G[base + t];
        w1[t] = ww.x; w2[t] = ww.y;
    } else if (t >= 512 && t < 512 + NNODE) {
        int i = t - 512;
        float2 g = g12G[base + i];
        g1s[i] = g.x; g2s[i] = g.y;
    }
    if (t < 64) biasl[t] = biasG[bh * 64 + t];
    __syncthreads();

    // issue first-pass gather loads (hidden under nothing heavy, but next
    // passes' loads hide under the scans)
    u16x8 raw;
    const bool gt = (t < NNODE * 2);
    const int gj = t >> 1, gq = (t & 1) * 8;
    int grow = 0;
    if (gt) {
        grow = perms[gj];
        raw = *(const u16x8*)(xp + ((long)b * NNODE + grow) * HO +
                              h * 64 + (half * 2) * 16 + gq);
    }

    const int c = t >> 4, o = t & 15;
    for (int p = 0; p < 2; ++p) {
        const int og2 = half * 2 + p;
        const int c0 = h * 64 + og2 * 16;

        if (gt) {
            #pragma unroll
            for (int oo = 0; oo < 8; ++oo) Vs[(gq + oo) * NP + gj] = bf2f(raw[oo]);
        }
        __syncthreads();                                    // B1
        if (p == 0 && gt)
            raw = *(const u16x8*)(xp + ((long)b * NNODE + grow) * HO +
                                  h * 64 + (og2 + 1) * 16 + gq);

        // merged chunk scans: S1 suffix then S2 prefix (thread-local pair)
        {
            float a1 = 0.0f;
            #pragma unroll
            for (int jj = 6; jj >= 0; --jj) {
                int j = c * 7 + jj;
                if (j < NNODE) {
                    a1 = fmaf(w1[j], Vs[o * NP + j], a1);
                    S1[o * NP + j] = a1;
                }
            }
            CT[c][o] = a1;
            float a2 = 0.0f;
            #pragma unroll
            for (int jj = 0; jj < 7; ++jj) {
                int j = c * 7 + jj;
                if (j < NNODE) {
                    float tmp = Vs[o * NP + j];
                    Vs[o * NP + j] = a2;
                    a2 = fmaf(w2[j], tmp, a2);
                }
            }
            CT2[c][o] = a2;
        }
        __syncthreads();                                    // B2
        // merged wave scans: CT suffix (shfl_down) + CT2 prefix (shfl_up)
        {
            float vA = CT[ln][w];
            float vB = CT2[ln][w];
            #pragma unroll
            for (int s = 1; s < 64; s <<= 1) {
                float tA = __shfl_down(vA, s, 64);
                float tB = __shfl_up(vB, s, 64);
                if (ln + s < 64) vA += tA;
                if (ln >= s)     vB += tB;
            }
            CT[ln][w] = vA;
            CT2[ln][w] = vB;
        }
        __syncthreads();                                    // B3
        // merged offset applies + boundary cells
        {
            float offA = (c < 63) ? CT[c + 1][o] : 0.0f;
            float offB = (c > 0) ? CT2[c - 1][o] : 0.0f;
            #pragma unroll
            for (int jj = 0; jj < 7; ++jj) {
                int j = c * 7 + jj;
                if (j < NNODE) {
                    S1[o * NP + j] += offA;
                    Vs[o * NP + j] += offB;
                }
            }
            if (c == 0)  S1[o * NP + NNODE] = 0.0f;
            if (c == 63) Vs[o * NP + NNODE] = CT2[63][o];
        }
        __syncthreads();                                    // B4

        // emit: nontemporal f32x4 per (row, col-quad)
        for (int idx = t; idx < NNODE * 4; idx += 1024) {
            int n = idx >> 2, q = (idx & 3) * 4;
            int tt = tls[n];
            float g1 = g1s[n], g2 = g2s[n];
            f32x4 r;
            #pragma unroll
            for (int rr = 0; rr < 4; ++rr) {
                int oo = q + rr;
                float v = g1 * S1[oo * NP + tt] + g2 * Vs[oo * NP + tt] +
                          biasl[og2 * 16 + oo];
                r[rr] = (v > 0.0f) ? v : (__expf(v) - 1.0f);
            }
            __builtin_nontemporal_store(
                r, (f32x4*)(out + ((long)b * NNODE + n) * HO + c0 + q));
        }
        __syncthreads();                                    // B5
    }
}

extern "C" void kernel_launch(void* const* d_in, const int* in_sizes, int n_in,
                              void* d_out, int out_size, void* d_ws, size_t ws_size,
                              hipStream_t stream) {
    const float* x     = (const float*)d_in[0];   // [108,392,256]
    const float* w_mlp = (const float*)d_in[2];   // [256,256]
    const float* b_mlp = (const float*)d_in[3];   // [256]
    const float* kern  = (const float*)d_in[4];   // [256,4,64] == [256,256]
    const float* ask   = (const float*)d_in[5];   // [64,4,1]
    const float* ank   = (const float*)d_in[6];   // [64,4,1]
    const float* bias  = (const float*)d_in[7];   // [256]
    float* out = (float*)d_out;

    const long TENS = (long)MROWS * IDIM;         // 10,838,016
    float*  s0    = (float*)d_ws;                 // [B,H,N]
    float*  ng0   = s0 + SGH;
    float*  zbacc = ng0 + SGH;                    // [B,256] atomically built
    float2* w12G  = (float2*)(zbacc + (long)BATCH * IDIM);
    float2* g12G  = w12G + SGH;
    uint*   ptG   = (uint*)(g12G + SGH);
    float*  biasG = (float*)(ptG + SGH);          // [432*64]
    ushort* xp_bf = (ushort*)(biasG + (long)BATCH * HEADS * 64);
    ushort* wshuf = xp_bf + TENS;                 // [65536] frag-order w_mlp
    ushort* kshuf = wshuf + 65536;                // [65536] frag-order kernel

    dim3 blk(256);

    // 0) weight shuffle + zbacc zeroing (fused)
    wcvt<<<dim3(512), blk, 0, stream>>>(w_mlp, kern, wshuf, kshuf, zbacc);

    // 1) fused: mlp(sigmoid, LDS-only) -> col-sums -> xp0 + s0/ng0
    fused_gemm<<<dim3(13, BATCH), dim3(256), 0, stream>>>(
        x, wshuf, kshuf, b_mlp, zbacc, xp_bf, ask, ank, s0, ng0);

    // 2) attention stats once per (b,h): fold + sort + scans + thresholds
    attn_stats<<<dim3(BATCH * HEADS), dim3(512), 0, stream>>>(
        s0, ng0, zbacc, kern, ask, ank, bias, ptG, w12G, g12G, biasG);

    // 3) attention scan, split grid: 2 blocks per (b,h) x 2 passes each
    attn_scan<<<dim3(2, BATCH * HEADS), dim3(1024), 0, stream>>>(
        xp_bf, ptG, w12G, g12G, biasG, out);
}

// Round 16
// 170.332 us; speedup vs baseline: 1.0720x; 1.0255x over previous
//
#include <hip/hip_runtime.h>
#include <hip/hip_bf16.h>
#include <math.h>
#include <float.h>

// Problem constants (fixed by setup_inputs)
#define BATCH 108
#define NNODE 392
#define IDIM  256
#define HEADS 4
#define ODIM  64
#define HO    256            // HEADS*ODIM
#define MROWS (BATCH*NNODE)  // 42336
#define SGH   (BATCH*HEADS*NNODE)  // 169344

typedef __attribute__((ext_vector_type(8))) short bf16x8;
typedef __attribute__((ext_vector_type(8))) unsigned short u16x8;
typedef __attribute__((ext_vector_type(4))) float f32x4;

// exact RNE f32->bf16 (known-good; do NOT replace with v_cvt_pk_bf16_f32 —
// R1 showed that instruction's rounding breaks the absmax check: 7.6e-2 vs 7.8e-3)
__device__ __forceinline__ ushort f2bf(float f) {
    unsigned u = __float_as_uint(f);
    unsigned r = (u + 0x7FFFu + ((u >> 16) & 1u)) >> 16;   // RNE
    return (ushort)r;
}
__device__ __forceinline__ float bf2f(ushort h) {
    return __uint_as_float(((unsigned)h) << 16);
}
// fast sigmoid: v_mul + v_exp + v_add + v_rcp (kept from R2: VALUBusy 31->20%)
__device__ __forceinline__ float fsigmoid(float x) {
    float e = __expf(-x);
    return __builtin_amdgcn_rcpf(1.0f + e);
}

#define MSTR 264   // LDS row stride (256 + 8 pad)

// weight fragment fetch from pre-shuffled layout (wg/lane from scope)
#define FRAG(src, jn, k0t) \
    (*(const bf16x8*)((src) + ((((wg * 4 + (jn)) * 8 + (k0t)) << 9)) + lane * 8))

// ---------------------------------------------------------------------------
// Fused double-GEMM — unchanged from R6 (stable ~44-47 µs).
__global__ __launch_bounds__(256)
void fused_gemm(const float* __restrict__ x, const ushort* __restrict__ wshuf,
                const ushort* __restrict__ kshuf, const float* __restrict__ bmlp,
                float* __restrict__ zbacc, ushort* __restrict__ xp0,
                const float* __restrict__ askv, const float* __restrict__ ankv,
                float* __restrict__ s0, float* __restrict__ ng0)
{
    __shared__ __attribute__((aligned(16))) ushort AsMs[32 * MSTR]; // x bf16 / mlp bf16
    __shared__ float cs_lds[256];   // per-block mlp col sums (deferred atomic)

    const int t    = threadIdx.x;
    const int lane = t & 63;
    const int wg   = t >> 6;            // 0..3 col-group / head
    const int lr   = lane & 15, kq = lane >> 4;
    const int rb   = blockIdx.x;        // 0..12 row-block within batch
    const int b    = blockIdx.y;
    const int row0 = rb * 32;
    const long gbase = (long)b * NNODE;

    // 2-deep prefetch of phase-1 weight fragments (no LDS dep; overlaps staging)
    bf16x8 wreg[2][4];
    #pragma unroll
    for (int jn = 0; jn < 4; ++jn) {
        wreg[0][jn] = FRAG(wshuf, jn, 0);
        wreg[1][jn] = FRAG(wshuf, jn, 1);
    }

    // ---- stage 32x256 x block (fp32 -> bf16), coalesced ----
    {
        const float* xb = x + (gbase + row0) * 256;
        #pragma unroll
        for (int j = 0; j < 8; ++j) {
            int e4  = t + j * 256;
            int row = e4 >> 6;
            int col = (e4 & 63) * 4;
            float4 v = (row0 + row < NNODE)
                ? *(const float4*)(xb + (long)row * 256 + col)
                : make_float4(0.f, 0.f, 0.f, 0.f);
            *(ushort4*)&AsMs[row * MSTR + col] =
                make_ushort4(f2bf(v.x), f2bf(v.y), f2bf(v.z), f2bf(v.w));
        }
    }
    __syncthreads();                        // barrier 1

    f32x4 acc[4][2] = {};   // [jn][imL]

    // ---------------- phase 1: mlp = sigmoid(x @ W + b) ----------------
    {
        #pragma unroll
        for (int k0t = 0; k0t < 8; ++k0t) {
            bf16x8 xf0 = *(const bf16x8*)&AsMs[lr * MSTR + k0t * 32 + kq * 8];
            bf16x8 xf1 = *(const bf16x8*)&AsMs[(16 + lr) * MSTR + k0t * 32 + kq * 8];
            #pragma unroll
            for (int jn = 0; jn < 4; ++jn) {
                acc[jn][0] = __builtin_amdgcn_mfma_f32_16x16x32_bf16(
                    wreg[k0t & 1][jn], xf0, acc[jn][0], 0, 0, 0);
                acc[jn][1] = __builtin_amdgcn_mfma_f32_16x16x32_bf16(
                    wreg[k0t & 1][jn], xf1, acc[jn][1], 0, 0, 0);
            }
            if (k0t < 6) {
                #pragma unroll
                for (int jn = 0; jn < 4; ++jn)
                    wreg[k0t & 1][jn] = FRAG(wshuf, jn, k0t + 2);
            }
        }
    }

    // prefetch phase-2 buffer 0 (overlaps epilogue 1; drained at barrier 2)
    bf16x8 kreg[2][4];
    #pragma unroll
    for (int jn = 0; jn < 4; ++jn) kreg[0][jn] = FRAG(kshuf, jn, 0);

    __syncthreads();                        // barrier 2

    // ---- epilogue 1: sigmoid -> Ms (aliases x); col sums -> cs_lds ----
    {
        float4 bi[4];
        #pragma unroll
        for (int jn = 0; jn < 4; ++jn)
            bi[jn] = *(const float4*)(bmlp + 64 * wg + 16 * jn + 4 * kq);
        float cs[4][4] = {};
        #pragma unroll
        for (int imL = 0; imL < 2; ++imL) {
            const int r_ = 16 * imL + lr;
            const bool ok = row0 + r_ < NNODE;
            #pragma unroll
            for (int jn = 0; jn < 4; ++jn) {
                float v[4];
                v[0] = fsigmoid(acc[jn][imL][0] + bi[jn].x);
                v[1] = fsigmoid(acc[jn][imL][1] + bi[jn].y);
                v[2] = fsigmoid(acc[jn][imL][2] + bi[jn].z);
                v[3] = fsigmoid(acc[jn][imL][3] + bi[jn].w);
                *(ushort4*)&AsMs[r_ * MSTR + 64 * wg + 16 * jn + 4 * kq] =
                    make_ushort4(f2bf(v[0]), f2bf(v[1]), f2bf(v[2]), f2bf(v[3]));
                if (ok) {
                    cs[jn][0] += v[0]; cs[jn][1] += v[1];
                    cs[jn][2] += v[2]; cs[jn][3] += v[3];
                }
            }
        }
        #pragma unroll
        for (int jn = 0; jn < 4; ++jn)
            #pragma unroll
            for (int r = 0; r < 4; ++r) {
                float v = cs[jn][r];
                v += __shfl_xor(v, 1, 64);
                v += __shfl_xor(v, 2, 64);
                v += __shfl_xor(v, 4, 64);
                v += __shfl_xor(v, 8, 64);
                if (lr == 0)
                    cs_lds[64 * wg + 16 * jn + 4 * kq + r] = v;
            }
    }
    __syncthreads();                        // barrier 3

    // ---------------- phase 2: xp0 = 0.2 * (Ms @ K^T) ----------------
    #pragma unroll
    for (int jn = 0; jn < 4; ++jn)
        #pragma unroll
        for (int imL = 0; imL < 2; ++imL)
            acc[jn][imL] = f32x4{0.f, 0.f, 0.f, 0.f};

    // prefetch phase-2 buffer 1 (covered by k0t=0's LDS reads + MFMAs)
    #pragma unroll
    for (int jn = 0; jn < 4; ++jn) kreg[1][jn] = FRAG(kshuf, jn, 1);

    {
        #pragma unroll
        for (int k0t = 0; k0t < 8; ++k0t) {
            bf16x8 xf0 = *(const bf16x8*)&AsMs[lr * MSTR + k0t * 32 + kq * 8];
            bf16x8 xf1 = *(const bf16x8*)&AsMs[(16 + lr) * MSTR + k0t * 32 + kq * 8];
            #pragma unroll
            for (int jn = 0; jn < 4; ++jn) {
                acc[jn][0] = __builtin_amdgcn_mfma_f32_16x16x32_bf16(
                    kreg[k0t & 1][jn], xf0, acc[jn][0], 0, 0, 0);
                acc[jn][1] = __builtin_amdgcn_mfma_f32_16x16x32_bf16(
                    kreg[k0t & 1][jn], xf1, acc[jn][1], 0, 0, 0);
            }
            if (k0t < 6) {
                #pragma unroll
                for (int jn = 0; jn < 4; ++jn)
                    kreg[k0t & 1][jn] = FRAG(kshuf, jn, k0t + 2);
            }
        }
    }

    // ---- epilogue 2: xp0 stores + fused s0/ng0 projections ----
    {
        const int h = wg;
        float askr[4][4], ankr[4][4];
        #pragma unroll
        for (int jn = 0; jn < 4; ++jn)
            #pragma unroll
            for (int r = 0; r < 4; ++r) {
                int o = 16 * jn + 4 * kq + r;
                askr[jn][r] = askv[o * HEADS + h];
                ankr[jn][r] = ankv[o * HEADS + h];
            }
        #pragma unroll
        for (int imL = 0; imL < 2; ++imL) {
            const int r_ = 16 * imL + lr;
            const int lrow = row0 + r_;
            const bool ok = lrow < NNODE;
            float ps = 0.0f, pn = 0.0f;
            if (ok) {
                ushort* dst = xp0 + (gbase + lrow) * 256 + 64 * h + 4 * kq;
                #pragma unroll
                for (int jn = 0; jn < 4; ++jn) {
                    float v0 = 0.2f * acc[jn][imL][0];
                    float v1 = 0.2f * acc[jn][imL][1];
                    float v2 = 0.2f * acc[jn][imL][2];
                    float v3 = 0.2f * acc[jn][imL][3];
                    *(ushort4*)(dst + 16 * jn) =
                        make_ushort4(f2bf(v0), f2bf(v1), f2bf(v2), f2bf(v3));
                    ps += v0 * askr[jn][0] + v1 * askr[jn][1] +
                          v2 * askr[jn][2] + v3 * askr[jn][3];
                    pn += v0 * ankr[jn][0] + v1 * ankr[jn][1] +
                          v2 * ankr[jn][2] + v3 * ankr[jn][3];
                }
            }
            ps += __shfl_xor(ps, 16, 64);
            ps += __shfl_xor(ps, 32, 64);
            pn += __shfl_xor(pn, 16, 64);
            pn += __shfl_xor(pn, 32, 64);
            if (ok && kq == 0) {
                long si = ((long)b * HEADS + h) * NNODE + lrow;
                s0[si]  = ps;
                ng0[si] = pn;
            }
        }
    }

    // deferred zbacc accumulation (cs_lds complete since barrier 3)
    atomicAdd(&zbacc[b * 256 + t], cs_lds[t]);
}

// ---------------------------------------------------------------------------
// Weight transpose + bf16 + MFMA-fragment shuffle; also zeroes zbacc.
__global__ __launch_bounds__(256)
void wcvt(const float* __restrict__ w_mlp, const float* __restrict__ kern,
          ushort* __restrict__ wshuf, ushort* __restrict__ kshuf,
          float* __restrict__ zbacc)
{
    if (blockIdx.x < BATCH)
        zbacc[blockIdx.x * 256 + threadIdx.x] = 0.0f;
    long idx = (long)(blockIdx.x & 255) * 256 + threadIdx.x;   // 0..65535
    const float* src = (blockIdx.x < 256) ? w_mlp : kern;
    ushort* dst = (blockIdx.x < 256) ? wshuf : kshuf;
    int e    = idx & 7;
    int lane = (int)(idx >> 3) & 63;
    int k0t  = (int)(idx >> 9) & 7;
    int jn   = (int)(idx >> 12) & 3;
    int g    = (int)(idx >> 14);
    int n = 64 * g + 16 * jn + (lane & 15);
    int k = 32 * k0t + (lane >> 4) * 8 + e;
    dst[idx] = f2bf(src[(long)k * 256 + n]);
}

// ---------------------------------------------------------------------------
// attn_fused — R16 = R13 champion (best measured: 170.8 µs total) + one safe
// latency hide: s0/ng0 loads issued at kernel ENTRY (their addresses don't
// depend on the fold's sc/ngc — only the adds do), hiding HBM/L2 latency
// under the zbK fold's 3 barriers + 16-iter dot. R14/R15 mapped the
// fuse/split axis: replicated stats +11.8 µs, HBM round-trip split +3.9 µs
// -> this fused 4-pass shape is the optimum.
#define NP  (NNODE + 1)
__global__ __launch_bounds__(1024)
void attn_fused(const float* __restrict__ s0, const float* __restrict__ ng0,
                const float* __restrict__ zbacc, const float* __restrict__ kern,
                const float* __restrict__ askv, const float* __restrict__ ankv,
                const ushort* __restrict__ xp, const float* __restrict__ bias,
                float* __restrict__ out)
{
    __shared__ float  pool1[16 * NP];   // passes: Vs   | pre: key/perm/zsh/partK
    __shared__ float  pool2[16 * NP];   // passes: S1   | pre: D1/D2
    __shared__ float  CT[64][17];       // S1 cross-chunk (suffix)
    __shared__ float  CT2[64][17];      // S2 cross-chunk (prefix)
    __shared__ float  w1[NNODE], w2[NNODE];
    __shared__ float  g1s[NNODE], g2s[NNODE];
    __shared__ ushort tls[NNODE];
    __shared__ float  biasl[64];
    __shared__ float  wsumA[8], wsumB[8];
    __shared__ float  scs[2];

    float* const key   = pool1;                 // [512]
    int*   const perm  = (int*)(pool1 + 512);   // [512]
    float* const zsh   = pool1 + 1024;          // [256]
    float* const partK = pool1 + 1280;          // [16][64]
    float* const D1    = pool2;                 // [NNODE+1]
    float* const D2    = pool2 + 400;           // [NNODE+1]
    float* const Vs    = pool1;
    float* const S1    = pool2;

    const int t  = threadIdx.x;
    const int bh = blockIdx.x;
    const int b  = bh >> 2, h = bh & 3;
    const long base = (long)bh * NNODE;
    const int ln = t & 63, w = t >> 6;  // w in 0..15

    // early-issue s0/ng0 loads (addresses independent of the fold below;
    // latency hides under phase 0's barriers + dot product)
    float ng0v = 0.0f, s0v = 0.0f;
    if (t < NNODE) {
        ng0v = ng0[base + t];
        s0v  = s0[base + t];
    }

    // ---- phase 0: zbK fold -> sc/ngc + biasl (all 16 waves) ----
    if (t < IDIM) zsh[t] = zbacc[b * 256 + t] * (0.8f / (float)NNODE);
    __syncthreads();
    {
        float p = 0.0f;                 // chunk w: k = w*16..w*16+15, col ln
        #pragma unroll
        for (int kk = 0; kk < 16; ++kk) {
            int k = w * 16 + kk;
            p = fmaf(zsh[k], kern[(long)k * HO + h * 64 + ln], p);
        }
        partK[w * 64 + ln] = p;
    }
    __syncthreads();
    if (t < 64) {
        float zk = 0.0f;
        #pragma unroll
        for (int kc = 0; kc < 16; ++kc) zk += partK[kc * 64 + t];
        biasl[t] = bias[h * 64 + t] + zk;
        float ps = zk * askv[t * HEADS + h];
        float pn = zk * ankv[t * HEADS + h];
        #pragma unroll
        for (int off = 32; off; off >>= 1) {
            ps += __shfl_down(ps, off, 64);
            pn += __shfl_down(pn, off, 64);
        }
        if (t == 0) { scs[0] = ps; scs[1] = pn; }
    }
    __syncthreads();
    const float sc = scs[0], ngc = scs[1];

    // ---- phase 1: register bitonic sort over t<512 (barriers uniform) ----
    float rk = (t < NNODE) ? (ng0v + ngc) : FLT_MAX;
    int   rp = t;

    for (int k = 2; k <= 512; k <<= 1) {
        for (int j = k >> 1; j > 0; j >>= 1) {
            if (j >= 64) {
                __syncthreads();
                if (t < 512) { key[t] = rk; perm[t] = rp; }
                __syncthreads();
                if (t < 512) {
                    const bool dir = ((t & k) == 0);
                    const bool lower = ((t & j) == 0);
                    float ok_ = key[t ^ j];
                    int   op  = perm[t ^ j];
                    const bool sw = lower ? ((rk > ok_) == dir)
                                          : ((ok_ > rk) == dir);
                    if (sw) { rk = ok_; rp = op; }
                }
            } else {
                if (t < 512) {
                    const bool dir = ((t & k) == 0);
                    const bool lower = ((t & j) == 0);
                    float ok_ = __shfl_xor(rk, j, 64);
                    int   op  = __shfl_xor(rp, j, 64);
                    const bool sw = lower ? ((rk > ok_) == dir)
                                          : ((ok_ > rk) == dir);
                    if (sw) { rk = ok_; rp = op; }
                }
            }
        }
    }
    __syncthreads();
    if (t < 512) { key[t] = rk; perm[t] = rp; }   // publish sorted keys/perm

    // ---- phase 2: weights + wave-shfl scans (t<512) ----
    const float w1v = (t < NNODE) ? __expf(rk) : 0.0f;
    const float w2v = (t < NNODE) ? __expf(0.2f * rk) : 0.0f;
    if (t < NNODE) { w1[t] = w1v; w2[t] = w2v; }

    float v1 = w1v, v2 = 0.0f;
    if (t < 512) {
        // D1: inclusive suffix sum of w1v
        #pragma unroll
        for (int s = 1; s < 64; s <<= 1) {
            float tmp = __shfl_down(v1, s, 64);
            if (ln + s < 64) v1 += tmp;
        }
        // D2: exclusive prefix sum of w2v
        v2 = (ln >= 1) ? __shfl_up(w2v, 1, 64) : 0.0f;
        #pragma unroll
        for (int s = 1; s < 64; s <<= 1) {
            float tmp = __shfl_up(v2, s, 64);
            if (ln >= s) v2 += tmp;
        }
        const float wt2 = __shfl(v2, 63, 64) + __shfl(w2v, 63, 64);
        if (ln == 0) { wsumA[w] = v1; wsumB[w] = wt2; }
    }
    __syncthreads();

    // issue pass-0 gather loads now (perm published; perm/key regions of
    // pool1 are dead after this + the binary search below)
    u16x8 raw;
    const bool gt = (t < NNODE * 2);
    const int gj = t >> 1, gq = (t & 1) * 8;
    int grow = 0;
    if (gt) {
        grow = perm[gj];
        raw = *(const u16x8*)(xp + ((long)b * NNODE + grow) * HO + h * 64 + gq);
    }

    if (t < 512) {
        float off1 = 0.0f, off2 = 0.0f;
        for (int ww = w + 1; ww < 8; ++ww) off1 += wsumA[ww];
        for (int ww = 0; ww < w; ++ww)     off2 += wsumB[ww];
        if (t < NNODE) {
            D1[t] = v1 + off1;
            D2[t] = v2 + off2;
        }
        if (t == 0) {
            D1[NNODE] = 0.0f;
            float tot = 0.0f;
            #pragma unroll
            for (int ww = 0; ww < 8; ++ww) tot += wsumB[ww];
            D2[NNODE] = tot;
        }
    }
    __syncthreads();

    if (t < NNODE) {
        float sn = s0v + sc;
        float negs = -sn;
        int lo = 0, hi = NNODE;
        while (lo < hi) {
            int mid = (lo + hi) >> 1;
            if (key[mid] < negs) lo = mid + 1; else hi = mid;
        }
        float e1 = __expf(sn), e2 = __expf(0.2f * sn);
        float inv = __builtin_amdgcn_rcpf(e1 * D1[lo] + e2 * D2[lo]);
        g1s[t] = e1 * inv;
        g2s[t] = e2 * inv;
        tls[t] = (ushort)lo;
    }
    __syncthreads();    // after this barrier pool1/pool2 pre-pass data is dead

    // ---- phase 3: 4 passes x 16 o-cols, 5 barriers/pass ----
    const int c = t >> 4, o = t & 15;
    for (int og2 = 0; og2 < 4; ++og2) {
        const int c0 = h * 64 + og2 * 16;

        // scatter prefetched gather into column-major LDS (overwrites pool1)
        if (gt) {
            #pragma unroll
            for (int oo = 0; oo < 8; ++oo) Vs[(gq + oo) * NP + gj] = bf2f(raw[oo]);
        }
        __syncthreads();                                    // B1
        // issue next pass's loads (consumed after the emit barrier)
        if (og2 < 3 && gt)
            raw = *(const u16x8*)(xp + ((long)b * NNODE + grow) * HO +
                                  h * 64 + (og2 + 1) * 16 + gq);

        // merged chunk scans: S1 suffix then S2 prefix — same thread owns
        // the same (c,o) elements, so no barrier between them
        {
            float a1 = 0.0f;
            #pragma unroll
            for (int jj = 6; jj >= 0; --jj) {
                int j = c * 7 + jj;
                if (j < NNODE) {
                    a1 = fmaf(w1[j], Vs[o * NP + j], a1);
                    S1[o * NP + j] = a1;
                }
            }
            CT[c][o] = a1;
            float a2 = 0.0f;
            #pragma unroll
            for (int jj = 0; jj < 7; ++jj) {
                int j = c * 7 + jj;
                if (j < NNODE) {
                    float tmp = Vs[o * NP + j];
                    Vs[o * NP + j] = a2;
                    a2 = fmaf(w2[j], tmp, a2);
                }
            }
            CT2[c][o] = a2;
        }
        __syncthreads();                                    // B2
        // merged wave scans: CT suffix (shfl_down) + CT2 prefix (shfl_up)
        {
            float vA = CT[ln][w];
            float vB = CT2[ln][w];
            #pragma unroll
            for (int s = 1; s < 64; s <<= 1) {
                float tA = __shfl_down(vA, s, 64);
                float tB = __shfl_up(vB, s, 64);
                if (ln + s < 64) vA += tA;
                if (ln >= s)     vB += tB;
            }
            CT[ln][w] = vA;
            CT2[ln][w] = vB;
        }
        __syncthreads();                                    // B3
        // merged offset applies + boundary cells
        {
            float offA = (c < 63) ? CT[c + 1][o] : 0.0f;
            float offB = (c > 0) ? CT2[c - 1][o] : 0.0f;
            #pragma unroll
            for (int jj = 0; jj < 7; ++jj) {
                int j = c * 7 + jj;
                if (j < NNODE) {
                    S1[o * NP + j] += offA;
                    Vs[o * NP + j] += offB;
                }
            }
            if (c == 0)  S1[o * NP + NNODE] = 0.0f;
            if (c == 63) Vs[o * NP + NNODE] = CT2[63][o];
        }
        __syncthreads();                                    // B4

        // emit: nontemporal f32x4 (ext_vector) per (row, col-quad)
        for (int idx = t; idx < NNODE * 4; idx += 1024) {
            int n = idx >> 2, q = (idx & 3) * 4;
            int tt = tls[n];
            float g1 = g1s[n], g2 = g2s[n];
            f32x4 r;
            #pragma unroll
            for (int rr = 0; rr < 4; ++rr) {
                int oo = q + rr;
                float v = g1 * S1[oo * NP + tt] + g2 * Vs[oo * NP + tt] +
                          biasl[og2 * 16 + oo];
                r[rr] = (v > 0.0f) ? v : (__expf(v) - 1.0f);
            }
            __builtin_nontemporal_store(
                r, (f32x4*)(out + ((long)b * NNODE + n) * HO + c0 + q));
        }
        __syncthreads();                                    // B5
    }
}

extern "C" void kernel_launch(void* const* d_in, const int* in_sizes, int n_in,
                              void* d_out, int out_size, void* d_ws, size_t ws_size,
                              hipStream_t stream) {
    const float* x     = (const float*)d_in[0];   // [108,392,256]
    const float* w_mlp = (const float*)d_in[2];   // [256,256]
    const float* b_mlp = (const float*)d_in[3];   // [256]
    const float* kern  = (const float*)d_in[4];   // [256,4,64] == [256,256]
    const float* ask   = (const float*)d_in[5];   // [64,4,1]
    const float* ank   = (const float*)d_in[6];   // [64,4,1]
    const float* bias  = (const float*)d_in[7];   // [256]
    float* out = (float*)d_out;

    const long TENS = (long)MROWS * IDIM;         // 10,838,016
    float*  s0    = (float*)d_ws;                 // [B,H,N]
    float*  ng0   = s0 + SGH;
    float*  zbacc = ng0 + SGH;                    // [B,256] atomically built
    ushort* xp_bf = (ushort*)(zbacc + (long)BATCH * IDIM);  // [B,N,H*O] bf16
    ushort* wshuf = xp_bf + TENS;                 // [65536] frag-order w_mlp
    ushort* kshuf = wshuf + 65536;                // [65536] frag-order kernel

    dim3 blk(256);

    // 0) weight shuffle + zbacc zeroing (fused)
    wcvt<<<dim3(512), blk, 0, stream>>>(w_mlp, kern, wshuf, kshuf, zbacc);

    // 1) fused: mlp(sigmoid, LDS-only) -> col-sums -> xp0 + s0/ng0
    fused_gemm<<<dim3(13, BATCH), dim3(256), 0, stream>>>(
        x, wshuf, kshuf, b_mlp, zbacc, xp_bf, ask, ank, s0, ng0);

    // 2) fused attention: stats + 4 merged-phase scan passes (R13 champion
    //    shape + early s0/ng0 load issue)
    attn_fused<<<dim3(BATCH * HEADS), dim3(1024), 0, stream>>>(
        s0, ng0, zbacc, kern, ask, ank, xp_bf, bias, out);
}